// Round 5
// baseline (174.897 us; speedup 1.0000x reference)
//
#include <hip/hip_runtime.h>

// FeaturesLinear: out[b,:] = sum_{h<50} user_W[fid[b,h]] * rating_W[ridx[b,h]]
//                            + item_W[item_ids[b]] + bias
// B=16384, HIST=50, D=128. Segments contiguous (repeat(arange(B), 50)).
//
// R1-R4: ILP-invariant 63us @3.2TB/s past-L2 -> bound by random-line fill rate.
// R5: fp16 table in ws: main ~40us, total 174->164.
// R6: XCD slicing ([8][100001][16dim fp16], 3.2MB/slice < 4MiB L2, slice=blk&7).
//   FETCH 197->37MB (slice residency CONFIRMED) but main=43us, nothing
//   saturated, VGPR=32 AGAIN -> compiler sank loads into consumers, ~2 in
//   flight, serial L2-hit latency. Total 174.6 (worse: +pre-pass, main flat).
// R7 (this round): force 10-deep MLP with a register-keepalive asm between
//   load batch and consume (rule #17): compiler must materialize u0..u9 ->
//   one vmcnt(0) per batch of 10 overlapped gathers. launch_bounds(256,8)
//   caps VGPR<=64 (est 54). Predict VGPR ~56-64, main 43->~15-22us.

#define BATCH     16384
#define HIST      50
#define TOTAL     (BATCH * HIST)
#define UNROLL    10
#define DIM4      32                  // 128 floats = 32 float4
#define NROWS_U   100001
#define SLICES    8
#define SL_H4     (NROWS_U * 4)       // half4 units per slice = 400004
#define UT_H4     (SLICES * SL_H4)    // 3,200,032 half4 total
#define UT_BYTES  ((size_t)UT_H4 * 8) // 25,600,256 B
#define RPB       64                  // batch rows per main block
#define BLOCK     256

typedef unsigned long long ull;

struct __attribute__((aligned(8))) half4 { _Float16 x, y, z, w; };  // 8 B

// ---- Pre-pass: transpose+convert user_W to fp16 slices; pack ids ----
// grid (784, 9): y<8 => table slice y; y==8 => id packing.
__global__ __launch_bounds__(256) void convert_pack_kernel(
    const float4* __restrict__ src,      // [100001, 32] float4
    const int*    __restrict__ feature_ids,
    const float*  __restrict__ ratings,
    half4*        __restrict__ uT,       // [8][100001][4] half4
    int*          __restrict__ packed)   // [TOTAL]
{
    const int tid = blockIdx.x * 256 + threadIdx.x;
    const int stride = gridDim.x * 256;
    if (blockIdx.y < SLICES) {
        const int slice = blockIdx.y;
        half4* dst = uT + (size_t)slice * SL_H4;
        for (int i = tid; i < SL_H4; i += stride) {
            const int row = i >> 2, d = i & 3;
            const float4 v = src[row * DIM4 + slice * 4 + d];
            half4 h;
            h.x = (_Float16)v.x; h.y = (_Float16)v.y;
            h.z = (_Float16)v.z; h.w = (_Float16)v.w;
            dst[i] = h;
        }
    } else {
        for (int t = tid; t < TOTAL; t += stride) {
            const int fid  = feature_ids[t];
            // ratings are exact multiples of 0.5 in [0.5,5.0]: r*2-1 in [0,9].
            const int ridx = (int)(ratings[t] * 2.0f) - 1;
            packed[t] = (fid << 4) | ridx;
        }
    }
}

__device__ __forceinline__ void fma4(float4& acc, ull q, const float4 w) {
    union { ull q; _Float16 h[4]; } c; c.q = q;
    acc.x += (float)c.h[0] * w.x;
    acc.y += (float)c.h[1] * w.y;
    acc.z += (float)c.h[2] * w.z;
    acc.w += (float)c.h[3] * w.w;
}

// ---- Main kernel: one block = 64 batch rows x one 16-dim slice ----
__global__ __launch_bounds__(BLOCK, 8) void features_linear_sliced(
    const int*    __restrict__ packed,    // [TOTAL] (fid<<4|ridx)
    const int*    __restrict__ item_ids,  // [BATCH]
    const half4*  __restrict__ uT,        // [8][100001][4] half4 (ws)
    const float4* __restrict__ rating_W,  // [10, 32] float4
    const float4* __restrict__ item_W,    // [100000, 32] float4
    const float4* __restrict__ bias,      // [32] float4
    float4*       __restrict__ out)       // [BATCH, 32] float4
{
    __shared__ int    sh_pid[RPB * HIST];   // 12.8 KB
    __shared__ float4 sh_rW[10 * 4];        // 640 B: rating_W slice columns

    const int tid   = threadIdx.x;
    const int slice = blockIdx.x & 7;       // round-robin => XCD affinity
    const int grp   = blockIdx.x >> 3;

    if (tid < 40)
        sh_rW[tid] = rating_W[(tid >> 2) * DIM4 + slice * 4 + (tid & 3)];

    const int base = grp * (RPB * HIST);
    for (int i = tid; i < RPB * HIST; i += BLOCK)
        sh_pid[i] = packed[base + i];
    __syncthreads();

    const int row = tid >> 2;               // 0..63
    const int d   = tid & 3;                // half4 index within slice
    const int b   = grp * RPB + row;
    const int off = row * HIST;

    // 8B-unit view of this slice's table; lane reads row*4 + d.
    const ull* usq = (const ull*)(uT + (size_t)slice * SL_H4);

    float4 acc; acc.x = 0.f; acc.y = 0.f; acc.z = 0.f; acc.w = 0.f;

    for (int h = 0; h < HIST; h += UNROLL) {
        const int p0 = sh_pid[off + h + 0], p1 = sh_pid[off + h + 1];
        const int p2 = sh_pid[off + h + 2], p3 = sh_pid[off + h + 3];
        const int p4 = sh_pid[off + h + 4], p5 = sh_pid[off + h + 5];
        const int p6 = sh_pid[off + h + 6], p7 = sh_pid[off + h + 7];
        const int p8 = sh_pid[off + h + 8], p9 = sh_pid[off + h + 9];

        // Issue 10 independent 8B gathers (L2-resident slice).
        ull u0 = usq[(p0 >> 4) * 4 + d];
        ull u1 = usq[(p1 >> 4) * 4 + d];
        ull u2 = usq[(p2 >> 4) * 4 + d];
        ull u3 = usq[(p3 >> 4) * 4 + d];
        ull u4 = usq[(p4 >> 4) * 4 + d];
        ull u5 = usq[(p5 >> 4) * 4 + d];
        ull u6 = usq[(p6 >> 4) * 4 + d];
        ull u7 = usq[(p7 >> 4) * 4 + d];
        ull u8 = usq[(p8 >> 4) * 4 + d];
        ull u9 = usq[(p9 >> 4) * 4 + d];

        // Register keepalive: forces all 10 load results to be materialized
        // here (one vmcnt wait for the whole batch) instead of the allocator
        // sinking each load into its consumer (R2/R4/R6 failure mode).
        asm volatile("" : "+v"(u0), "+v"(u1), "+v"(u2), "+v"(u3), "+v"(u4),
                          "+v"(u5), "+v"(u6), "+v"(u7), "+v"(u8), "+v"(u9));

        fma4(acc, u0, sh_rW[(p0 & 15) * 4 + d]);
        fma4(acc, u1, sh_rW[(p1 & 15) * 4 + d]);
        fma4(acc, u2, sh_rW[(p2 & 15) * 4 + d]);
        fma4(acc, u3, sh_rW[(p3 & 15) * 4 + d]);
        fma4(acc, u4, sh_rW[(p4 & 15) * 4 + d]);
        fma4(acc, u5, sh_rW[(p5 & 15) * 4 + d]);
        fma4(acc, u6, sh_rW[(p6 & 15) * 4 + d]);
        fma4(acc, u7, sh_rW[(p7 & 15) * 4 + d]);
        fma4(acc, u8, sh_rW[(p8 & 15) * 4 + d]);
        fma4(acc, u9, sh_rW[(p9 & 15) * 4 + d]);
    }

    const int    iid = item_ids[b];
    const float4 iw  = item_W[iid * DIM4 + slice * 4 + d];
    const float4 bs  = bias[slice * 4 + d];

    float4 o;
    o.x = acc.x + iw.x + bs.x;
    o.y = acc.y + iw.y + bs.y;
    o.z = acc.z + iw.z + bs.z;
    o.w = acc.w + iw.w + bs.w;
    out[b * DIM4 + slice * 4 + d] = o;
}

// ---- fp32 fallback (R4 structure) if workspace too small ----
__global__ __launch_bounds__(BLOCK) void features_linear_f32(
    const int*    __restrict__ feature_ids,
    const float*  __restrict__ ratings,
    const int*    __restrict__ item_ids,
    const float4* __restrict__ user_W,
    const float4* __restrict__ rating_W,
    const float4* __restrict__ item_W,
    const float4* __restrict__ bias,
    float4*       __restrict__ out)
{
    __shared__ float4 sh_rW[10 * DIM4];
    __shared__ int    sh_fid[8 * HIST];
    __shared__ int    sh_ridx[8 * HIST];

    const int tid = threadIdx.x;
    for (int i = tid; i < 10 * DIM4; i += BLOCK) sh_rW[i] = rating_W[i];
    const int base = blockIdx.x * (8 * HIST);
    for (int i = tid; i < 8 * HIST; i += BLOCK) {
        sh_fid[i] = feature_ids[base + i];
        float r = ratings[base + i];
        sh_ridx[i] = (int)(r * 2.0f) - 1;
    }
    __syncthreads();

    const int row = tid >> 5;
    const int d4  = tid & 31;
    const int b   = blockIdx.x * 8 + row;

    float4 acc; acc.x = 0.f; acc.y = 0.f; acc.z = 0.f; acc.w = 0.f;
    const int off = row * HIST;

    for (int h = 0; h < HIST; h += UNROLL) {
        int f[UNROLL], r[UNROLL];
#pragma unroll
        for (int i = 0; i < UNROLL; ++i) {
            f[i] = sh_fid[off + h + i];
            r[i] = sh_ridx[off + h + i];
        }
        float4 u[UNROLL];
#pragma unroll
        for (int i = 0; i < UNROLL; ++i) u[i] = user_W[f[i] * DIM4 + d4];
#pragma unroll
        for (int i = 0; i < UNROLL; ++i) {
            const float4 w = sh_rW[r[i] * DIM4 + d4];
            acc.x += u[i].x * w.x;
            acc.y += u[i].y * w.y;
            acc.z += u[i].z * w.z;
            acc.w += u[i].w * w.w;
        }
    }

    const int    iid = item_ids[b];
    const float4 iw  = item_W[iid * DIM4 + d4];
    const float4 bs  = bias[d4];

    float4 o;
    o.x = acc.x + iw.x + bs.x;
    o.y = acc.y + iw.y + bs.y;
    o.z = acc.z + iw.z + bs.z;
    o.w = acc.w + iw.w + bs.w;
    out[b * DIM4 + d4] = o;
}

extern "C" void kernel_launch(void* const* d_in, const int* in_sizes, int n_in,
                              void* d_out, int out_size, void* d_ws, size_t ws_size,
                              hipStream_t stream) {
    const int*    feature_ids = (const int*)   d_in[0];
    const float*  ratings     = (const float*) d_in[1];
    // d_in[2] = segment_ids: unused (segments contiguous by construction)
    const int*    item_ids    = (const int*)   d_in[3];
    const float4* user_W      = (const float4*)d_in[4];
    const float4* rating_W    = (const float4*)d_in[5];
    const float4* item_W      = (const float4*)d_in[6];
    const float4* bias        = (const float4*)d_in[7];
    float4*       out         = (float4*)      d_out;

    const size_t need = UT_BYTES + (size_t)TOTAL * sizeof(int); // ~28.9 MB
    if (d_ws != nullptr && ws_size >= need) {
        half4* uT     = (half4*)d_ws;
        int*   packed = (int*)((char*)d_ws + UT_BYTES);

        convert_pack_kernel<<<dim3(784, 9), dim3(256), 0, stream>>>(
            user_W, feature_ids, ratings, uT, packed);

        features_linear_sliced<<<dim3((BATCH / RPB) * SLICES), dim3(BLOCK), 0, stream>>>(
            packed, item_ids, uT, rating_W, item_W, bias, out);
    } else {
        features_linear_f32<<<dim3(BATCH / 8), dim3(BLOCK), 0, stream>>>(
            feature_ids, ratings, item_ids, user_W, rating_W, item_W, bias, out);
    }
}

// Round 7
// 167.896 us; speedup vs baseline: 1.0417x; 1.0417x over previous
//
#include <hip/hip_runtime.h>

// FeaturesLinear: out[b,:] = sum_{h<50} user_W[fid[b,h]] * rating_W[ridx[b,h]]
//                            + item_W[item_ids[b]] + bias
// B=16384, HIST=50, D=128. Segments contiguous (repeat(arange(B), 50)).
//
// R1-R4: 63us, invariant to ILP -> past-L2 fill wall (197MB @3.2TB/s).
// R5: fp16 table: main ~40us (fill 120MB @3.2 = 37us).
// R6: 8x16-dim slices, L2-resident: FETCH 197->37MB but main=43us.
// R7: keepalive asm FORCED 10 loads in flight -> zero change. MLP falsified.
//   43.0us == 1600 gather-instr/CU x 16 random lines x ~4cy = 42.7us:
//   bound by CU vector-memory front-end line-request rate.
// R8: 4 slices x 32 contiguous dims = one 64B line per gather (lines
//   6.55M->3.28M). FAILED: sh_rW staged with `if(tid<320)` under BLOCK=256
//   -> rating rows 8,9 uninitialized (absmax 1.63). Theory untested.
// R9 (this round): fix staging to strided loop; rest identical to R8.
//   Predict main 43->~22-28us, VGPR ~70-100, total ~152-158, absmax 9.77e-4.

#define BATCH     16384
#define HIST      50
#define TOTAL     (BATCH * HIST)
#define UNROLL    10
#define DIM4      32                  // 128 floats = 32 float4
#define NROWS_U   100001
#define SLICES    4
#define SL_U4     (NROWS_U * 4)       // 16B units per slice (row = 4 x 16B = 64B)
#define UT_BYTES  ((size_t)SLICES * SL_U4 * 16)  // 25,600,256 B
#define RPB       64                  // batch rows per main block
#define BLOCK     256
#define RWPAD     36                  // rating_W LDS row stride (floats), pad vs 32

typedef unsigned int u32x4 __attribute__((ext_vector_type(4)));

// ---- Pre-pass: transpose+convert user_W into 4 slices of 32 dims (64B fp16
//      rows, 64B-aligned => one cache line per gather); pack ids. ----
// grid (784, 5): y<4 => table slice y; y==4 => id packing.
__global__ __launch_bounds__(256) void convert_pack_kernel(
    const float4* __restrict__ src,      // [100001, 32] float4
    const int*    __restrict__ feature_ids,
    const float*  __restrict__ ratings,
    u32x4*        __restrict__ uT,       // [4][100001][4] 16B units
    int*          __restrict__ packed)   // [TOTAL]
{
    const int tid = blockIdx.x * 256 + threadIdx.x;
    const int stride = gridDim.x * 256;
    if (blockIdx.y < SLICES) {
        const int slice = blockIdx.y;
        u32x4* dst = uT + (size_t)slice * SL_U4;
        for (int i = tid; i < SL_U4; i += stride) {
            const int row = i >> 2, q = i & 3;   // q: which 16B of the 64B row
            const float4 a = src[row * DIM4 + slice * 8 + q * 2];
            const float4 b = src[row * DIM4 + slice * 8 + q * 2 + 1];
            union { u32x4 v; _Float16 h[8]; } o;
            o.h[0] = (_Float16)a.x; o.h[1] = (_Float16)a.y;
            o.h[2] = (_Float16)a.z; o.h[3] = (_Float16)a.w;
            o.h[4] = (_Float16)b.x; o.h[5] = (_Float16)b.y;
            o.h[6] = (_Float16)b.z; o.h[7] = (_Float16)b.w;
            dst[i] = o.v;
        }
    } else {
        for (int t = tid; t < TOTAL; t += stride) {
            const int fid  = feature_ids[t];
            // ratings are exact multiples of 0.5 in [0.5,5.0]: r*2-1 in [0,9].
            const int ridx = (int)(ratings[t] * 2.0f) - 1;
            packed[t] = (fid << 4) | ridx;
        }
    }
}

// ---- Main kernel: one block = 64 batch rows x one 32-dim slice ----
// 4-lane group gathers one full 64B line per (b,h). slice = blockIdx&3.
__global__ __launch_bounds__(BLOCK, 4) void features_linear_sliced(
    const int*    __restrict__ packed,    // [TOTAL] (fid<<4|ridx)
    const int*    __restrict__ item_ids,  // [BATCH]
    const u32x4*  __restrict__ uT,        // [4][100001][4] (ws)
    const float*  __restrict__ rating_Wf, // [10, 128] floats
    const float4* __restrict__ item_W,    // [100000, 32] float4
    const float4* __restrict__ bias,      // [32] float4
    float4*       __restrict__ out)       // [BATCH, 32] float4
{
    __shared__ int   sh_pid[RPB * HIST];     // 12.8 KB
    __shared__ float sh_rW[10 * RWPAD];      // 1.44 KB, padded stride 36

    const int tid   = threadIdx.x;
    const int slice = blockIdx.x & 3;
    const int grp   = blockIdx.x >> 2;

    // R8 BUG WAS HERE: `if (tid < 320)` with 256 threads left rows 8,9
    // unwritten. Strided loop covers all 10*32=320 elements.
    for (int i = tid; i < 10 * 32; i += BLOCK) {
        const int r = i >> 5, j = i & 31;
        sh_rW[r * RWPAD + j] = rating_Wf[r * 128 + slice * 32 + j];
    }

    const int base = grp * (RPB * HIST);
    for (int i = tid; i < RPB * HIST; i += BLOCK)
        sh_pid[i] = packed[base + i];
    __syncthreads();

    const int row = tid >> 2;               // 0..63
    const int q   = tid & 3;                // which 16B of the 64B row-slice
    const int b   = grp * RPB + row;
    const int off = row * HIST;

    const u32x4* us = uT + (size_t)slice * SL_U4;

    float a0 = 0.f, a1 = 0.f, a2 = 0.f, a3 = 0.f,
          a4 = 0.f, a5 = 0.f, a6 = 0.f, a7 = 0.f;

    for (int h = 0; h < HIST; h += UNROLL) {
        const int p0 = sh_pid[off + h + 0], p1 = sh_pid[off + h + 1];
        const int p2 = sh_pid[off + h + 2], p3 = sh_pid[off + h + 3];
        const int p4 = sh_pid[off + h + 4], p5 = sh_pid[off + h + 5];
        const int p6 = sh_pid[off + h + 6], p7 = sh_pid[off + h + 7];
        const int p8 = sh_pid[off + h + 8], p9 = sh_pid[off + h + 9];

        // 10 independent 16B gathers; each 4-lane group covers one 64B line.
        u32x4 u0 = us[(p0 >> 4) * 4 + q];
        u32x4 u1 = us[(p1 >> 4) * 4 + q];
        u32x4 u2 = us[(p2 >> 4) * 4 + q];
        u32x4 u3 = us[(p3 >> 4) * 4 + q];
        u32x4 u4 = us[(p4 >> 4) * 4 + q];
        u32x4 u5 = us[(p5 >> 4) * 4 + q];
        u32x4 u6 = us[(p6 >> 4) * 4 + q];
        u32x4 u7 = us[(p7 >> 4) * 4 + q];
        u32x4 u8 = us[(p8 >> 4) * 4 + q];
        u32x4 u9 = us[(p9 >> 4) * 4 + q];

        // Keepalive: batch the 10 loads behind a single wait (R7 discipline).
        asm volatile("" : "+v"(u0), "+v"(u1), "+v"(u2), "+v"(u3), "+v"(u4),
                          "+v"(u5), "+v"(u6), "+v"(u7), "+v"(u8), "+v"(u9));

#define CONSUME(uk, pk)                                                  \
        {                                                                \
            union { u32x4 v; _Float16 hh[8]; } c; c.v = uk;              \
            const float* w = &sh_rW[(pk & 15) * RWPAD + q * 8];          \
            a0 += (float)c.hh[0] * w[0]; a1 += (float)c.hh[1] * w[1];    \
            a2 += (float)c.hh[2] * w[2]; a3 += (float)c.hh[3] * w[3];    \
            a4 += (float)c.hh[4] * w[4]; a5 += (float)c.hh[5] * w[5];    \
            a6 += (float)c.hh[6] * w[6]; a7 += (float)c.hh[7] * w[7];    \
        }
        CONSUME(u0, p0) CONSUME(u1, p1) CONSUME(u2, p2) CONSUME(u3, p3)
        CONSUME(u4, p4) CONSUME(u5, p5) CONSUME(u6, p6) CONSUME(u7, p7)
        CONSUME(u8, p8) CONSUME(u9, p9)
#undef CONSUME
    }

    const int    iid = item_ids[b];
    const int    e   = slice * 8 + q * 2;          // float4 index of dims
    const float4 iw0 = item_W[iid * DIM4 + e];
    const float4 iw1 = item_W[iid * DIM4 + e + 1];
    const float4 bs0 = bias[e];
    const float4 bs1 = bias[e + 1];

    float4 o0, o1;
    o0.x = a0 + iw0.x + bs0.x; o0.y = a1 + iw0.y + bs0.y;
    o0.z = a2 + iw0.z + bs0.z; o0.w = a3 + iw0.w + bs0.w;
    o1.x = a4 + iw1.x + bs1.x; o1.y = a5 + iw1.y + bs1.y;
    o1.z = a6 + iw1.z + bs1.z; o1.w = a7 + iw1.w + bs1.w;
    out[b * DIM4 + e]     = o0;
    out[b * DIM4 + e + 1] = o1;
}

// ---- fp32 fallback (R4 structure) if workspace too small ----
__global__ __launch_bounds__(BLOCK) void features_linear_f32(
    const int*    __restrict__ feature_ids,
    const float*  __restrict__ ratings,
    const int*    __restrict__ item_ids,
    const float4* __restrict__ user_W,
    const float4* __restrict__ rating_W,
    const float4* __restrict__ item_W,
    const float4* __restrict__ bias,
    float4*       __restrict__ out)
{
    __shared__ float4 sh_rW[10 * DIM4];
    __shared__ int    sh_fid[8 * HIST];
    __shared__ int    sh_ridx[8 * HIST];

    const int tid = threadIdx.x;
    for (int i = tid; i < 10 * DIM4; i += BLOCK) sh_rW[i] = rating_W[i];
    const int base = blockIdx.x * (8 * HIST);
    for (int i = tid; i < 8 * HIST; i += BLOCK) {
        sh_fid[i] = feature_ids[base + i];
        float r = ratings[base + i];
        sh_ridx[i] = (int)(r * 2.0f) - 1;
    }
    __syncthreads();

    const int row = tid >> 5;
    const int d4  = tid & 31;
    const int b   = blockIdx.x * 8 + row;

    float4 acc; acc.x = 0.f; acc.y = 0.f; acc.z = 0.f; acc.w = 0.f;
    const int off = row * HIST;

    for (int h = 0; h < HIST; h += UNROLL) {
        int f[UNROLL], r[UNROLL];
#pragma unroll
        for (int i = 0; i < UNROLL; ++i) {
            f[i] = sh_fid[off + h + i];
            r[i] = sh_ridx[off + h + i];
        }
        float4 u[UNROLL];
#pragma unroll
        for (int i = 0; i < UNROLL; ++i) u[i] = user_W[f[i] * DIM4 + d4];
#pragma unroll
        for (int i = 0; i < UNROLL; ++i) {
            const float4 w = sh_rW[r[i] * DIM4 + d4];
            acc.x += u[i].x * w.x;
            acc.y += u[i].y * w.y;
            acc.z += u[i].z * w.z;
            acc.w += u[i].w * w.w;
        }
    }

    const int    iid = item_ids[b];
    const float4 iw  = item_W[iid * DIM4 + d4];
    const float4 bs  = bias[d4];

    float4 o;
    o.x = acc.x + iw.x + bs.x;
    o.y = acc.y + iw.y + bs.y;
    o.z = acc.z + iw.z + bs.z;
    o.w = acc.w + iw.w + bs.w;
    out[b * DIM4 + d4] = o;
}

extern "C" void kernel_launch(void* const* d_in, const int* in_sizes, int n_in,
                              void* d_out, int out_size, void* d_ws, size_t ws_size,
                              hipStream_t stream) {
    const int*    feature_ids = (const int*)   d_in[0];
    const float*  ratings     = (const float*) d_in[1];
    // d_in[2] = segment_ids: unused (segments contiguous by construction)
    const int*    item_ids    = (const int*)   d_in[3];
    const float4* user_W      = (const float4*)d_in[4];
    const float4* rating_W    = (const float4*)d_in[5];
    const float4* item_W      = (const float4*)d_in[6];
    const float4* bias        = (const float4*)d_in[7];
    float4*       out         = (float4*)      d_out;

    const size_t need = UT_BYTES + (size_t)TOTAL * sizeof(int); // ~28.9 MB
    if (d_ws != nullptr && ws_size >= need) {
        u32x4* uT     = (u32x4*)d_ws;
        int*   packed = (int*)((char*)d_ws + UT_BYTES);

        convert_pack_kernel<<<dim3(784, 5), dim3(256), 0, stream>>>(
            user_W, feature_ids, ratings, uT, packed);

        features_linear_sliced<<<dim3((BATCH / RPB) * SLICES), dim3(BLOCK), 0, stream>>>(
            packed, item_ids, uT, (const float*)rating_W, item_W, bias, out);
    } else {
        features_linear_f32<<<dim3(BATCH / 8), dim3(BLOCK), 0, stream>>>(
            feature_ids, ratings, item_ids, user_W, rating_W, item_W, bias, out);
    }
}

// Round 8
// 164.858 us; speedup vs baseline: 1.0609x; 1.0184x over previous
//
#include <hip/hip_runtime.h>

// FeaturesLinear: out[b,:] = sum_{h<50} user_W[fid[b,h]] * rating_W[ridx[b,h]]
//                            + item_W[item_ids[b]] + bias
// B=16384, HIST=50, D=128. Segments contiguous (repeat(arange(B), 50)).
//
// Session model (validated R1/R5/R6/R9): dur_us = 70 fixed + 41 ws-fill + kernels.
// R1-R4: 63us invariant to ILP -> past-L2 fill wall (197MB @3.2TB/s).
// R7: keepalive-forced 10-deep MLP -> zero change. MLP falsified; bound by
//   CU line-request rate (~4cy per distinct 64B line).
// R9: 4 slices x 32 dims = one 64B line/gather: main 43->~37us. Request wall
//   is 21.3us; excess ~16us = L3 service (slice ws 6.4MB > 4MiB L2, ~38% miss
//   -> 79MB @3.2TB/s) + cold redistribution, at only 16 waves/CU.
// R10 (this round): overlap request stream with L3 service + streamline convert.
//   (a) RPB 32, h-split within block (two 25-h halves, LDS reduce) -> 2048
//       blocks, 32 waves/CU, UNROLL 5 (VGPR fits <=64 at launch_bounds(256,8)).
//   (b) convert rewritten as pure linear stream (read float4 pair at 2n).
//   Predict: convert ~13-15us, main ~27-32us, dur ~152-158, absmax 9.77e-4.

#define BATCH     16384
#define HIST      50
#define TOTAL     (BATCH * HIST)
#define UNROLL    5
#define DIM4      32                  // 128 floats = 32 float4
#define NROWS_U   100001
#define SLICES    4
#define SL_U4     (NROWS_U * 4)       // 16B units per slice (row = 64B)
#define UT_BYTES  ((size_t)SLICES * SL_U4 * 16)  // 25,600,256 B
#define RPB       32                  // batch rows per main block
#define BLOCK     256
#define RWPAD     36                  // rating_W LDS row stride (floats)

typedef unsigned int u32x4 __attribute__((ext_vector_type(4)));

// ---- Pre-pass: fp32->fp16 slice transpose (pure stream) + id packing ----
// Unit n (16B out) = (row, slice, q): reads float4 pair at src[2n], src[2n+1]
// (perfectly linear), writes uT[slice][row*4+q]. grid (2048, 2): y1 = packing.
__global__ __launch_bounds__(256) void convert_pack_kernel(
    const float4* __restrict__ src,      // [100001, 32] float4
    const int*    __restrict__ feature_ids,
    const float*  __restrict__ ratings,
    u32x4*        __restrict__ uT,       // [4][100001][4] 16B units
    int*          __restrict__ packed)   // [TOTAL]
{
    const int tid = blockIdx.x * 256 + threadIdx.x;
    const int stride = gridDim.x * 256;
    if (blockIdx.y == 0) {
        for (int n = tid; n < NROWS_U * 16; n += stride) {
            const int row = n >> 4, s = (n >> 2) & 3, q = n & 3;
            const float4 a = src[2 * n];
            const float4 b = src[2 * n + 1];
            union { u32x4 v; _Float16 h[8]; } o;
            o.h[0] = (_Float16)a.x; o.h[1] = (_Float16)a.y;
            o.h[2] = (_Float16)a.z; o.h[3] = (_Float16)a.w;
            o.h[4] = (_Float16)b.x; o.h[5] = (_Float16)b.y;
            o.h[6] = (_Float16)b.z; o.h[7] = (_Float16)b.w;
            uT[(size_t)s * SL_U4 + row * 4 + q] = o.v;
        }
    } else {
        for (int t = tid; t < TOTAL; t += stride) {
            const int fid  = feature_ids[t];
            // ratings are exact multiples of 0.5 in [0.5,5.0]: r*2-1 in [0,9].
            const int ridx = (int)(ratings[t] * 2.0f) - 1;
            packed[t] = (fid << 4) | ridx;
        }
    }
}

// ---- Main: block = 32 batch rows x one 32-dim slice; h split in two halves
//      across the block's two wave-pairs, LDS-reduced at the end. ----
__global__ __launch_bounds__(BLOCK, 8) void features_linear_sliced(
    const int*    __restrict__ packed,    // [TOTAL] (fid<<4|ridx)
    const int*    __restrict__ item_ids,  // [BATCH]
    const u32x4*  __restrict__ uT,        // [4][100001][4] (ws)
    const float*  __restrict__ rating_Wf, // [10, 128] floats
    const float4* __restrict__ item_W,    // [100000, 32] float4
    const float4* __restrict__ bias,      // [32] float4
    float4*       __restrict__ out)       // [BATCH, 32] float4
{
    __shared__ int   sh_pid[RPB * HIST];     // 6.4 KB
    __shared__ float sh_rW[10 * RWPAD];      // 1.44 KB
    __shared__ float sh_red[128][8];         // 4 KB: h-half partials

    const int tid   = threadIdx.x;
    const int slice = blockIdx.x & 3;
    const int grp   = blockIdx.x >> 2;

    for (int i = tid; i < 10 * 32; i += BLOCK) {
        const int r = i >> 5, j = i & 31;
        sh_rW[r * RWPAD + j] = rating_Wf[r * 128 + slice * 32 + j];
    }
    const int base = grp * (RPB * HIST);
    for (int i = tid; i < RPB * HIST; i += BLOCK)
        sh_pid[i] = packed[base + i];
    __syncthreads();

    const int quad = tid >> 2;          // 0..63
    const int q    = tid & 3;           // 16B unit within the 64B row-slice
    const int row  = quad & 31;         // 0..31 batch row within group
    const int hh   = quad >> 5;         // h-half: 0 -> h<25, 1 -> h>=25
    const int off  = row * HIST + hh * 25;

    const u32x4* us = uT + (size_t)slice * SL_U4;

    float a0 = 0.f, a1 = 0.f, a2 = 0.f, a3 = 0.f,
          a4 = 0.f, a5 = 0.f, a6 = 0.f, a7 = 0.f;

    for (int h = 0; h < 25; h += UNROLL) {
        const int p0 = sh_pid[off + h + 0], p1 = sh_pid[off + h + 1];
        const int p2 = sh_pid[off + h + 2], p3 = sh_pid[off + h + 3];
        const int p4 = sh_pid[off + h + 4];

        u32x4 u0 = us[(p0 >> 4) * 4 + q];
        u32x4 u1 = us[(p1 >> 4) * 4 + q];
        u32x4 u2 = us[(p2 >> 4) * 4 + q];
        u32x4 u3 = us[(p3 >> 4) * 4 + q];
        u32x4 u4 = us[(p4 >> 4) * 4 + q];

        asm volatile("" : "+v"(u0), "+v"(u1), "+v"(u2), "+v"(u3), "+v"(u4));

#define CONSUME(uk, pk)                                                  \
        {                                                                \
            union { u32x4 v; _Float16 hh_[8]; } c; c.v = uk;             \
            const float* w = &sh_rW[(pk & 15) * RWPAD + q * 8];          \
            a0 += (float)c.hh_[0] * w[0]; a1 += (float)c.hh_[1] * w[1];  \
            a2 += (float)c.hh_[2] * w[2]; a3 += (float)c.hh_[3] * w[3];  \
            a4 += (float)c.hh_[4] * w[4]; a5 += (float)c.hh_[5] * w[5];  \
            a6 += (float)c.hh_[6] * w[6]; a7 += (float)c.hh_[7] * w[7];  \
        }
        CONSUME(u0, p0) CONSUME(u1, p1) CONSUME(u2, p2)
        CONSUME(u3, p3) CONSUME(u4, p4)
#undef CONSUME
    }

    // Reduce the two h-halves: upper half parks partials in LDS.
    if (hh == 1) {
        float* d = &sh_red[row * 4 + q][0];
        d[0] = a0; d[1] = a1; d[2] = a2; d[3] = a3;
        d[4] = a4; d[5] = a5; d[6] = a6; d[7] = a7;
    }
    __syncthreads();
    if (hh == 0) {
        const float* p = &sh_red[row * 4 + q][0];
        a0 += p[0]; a1 += p[1]; a2 += p[2]; a3 += p[3];
        a4 += p[4]; a5 += p[5]; a6 += p[6]; a7 += p[7];

        const int    b   = grp * RPB + row;
        const int    iid = item_ids[b];
        const int    e   = slice * 8 + q * 2;      // float4 index of dims
        const float4 iw0 = item_W[iid * DIM4 + e];
        const float4 iw1 = item_W[iid * DIM4 + e + 1];
        const float4 bs0 = bias[e];
        const float4 bs1 = bias[e + 1];

        float4 o0, o1;
        o0.x = a0 + iw0.x + bs0.x; o0.y = a1 + iw0.y + bs0.y;
        o0.z = a2 + iw0.z + bs0.z; o0.w = a3 + iw0.w + bs0.w;
        o1.x = a4 + iw1.x + bs1.x; o1.y = a5 + iw1.y + bs1.y;
        o1.z = a6 + iw1.z + bs1.z; o1.w = a7 + iw1.w + bs1.w;
        out[b * DIM4 + e]     = o0;
        out[b * DIM4 + e + 1] = o1;
    }
}

// ---- fp32 fallback (R4 structure) if workspace too small ----
__global__ __launch_bounds__(BLOCK) void features_linear_f32(
    const int*    __restrict__ feature_ids,
    const float*  __restrict__ ratings,
    const int*    __restrict__ item_ids,
    const float4* __restrict__ user_W,
    const float4* __restrict__ rating_W,
    const float4* __restrict__ item_W,
    const float4* __restrict__ bias,
    float4*       __restrict__ out)
{
    __shared__ float4 sh_rW[10 * DIM4];
    __shared__ int    sh_fid[8 * HIST];
    __shared__ int    sh_ridx[8 * HIST];

    const int tid = threadIdx.x;
    for (int i = tid; i < 10 * DIM4; i += BLOCK) sh_rW[i] = rating_W[i];
    const int base = blockIdx.x * (8 * HIST);
    for (int i = tid; i < 8 * HIST; i += BLOCK) {
        sh_fid[i] = feature_ids[base + i];
        float r = ratings[base + i];
        sh_ridx[i] = (int)(r * 2.0f) - 1;
    }
    __syncthreads();

    const int row = tid >> 5;
    const int d4  = tid & 31;
    const int b   = blockIdx.x * 8 + row;

    float4 acc; acc.x = 0.f; acc.y = 0.f; acc.z = 0.f; acc.w = 0.f;
    const int off = row * HIST;

    for (int h = 0; h < HIST; h += 10) {
        int f[10], r[10];
#pragma unroll
        for (int i = 0; i < 10; ++i) {
            f[i] = sh_fid[off + h + i];
            r[i] = sh_ridx[off + h + i];
        }
        float4 u[10];
#pragma unroll
        for (int i = 0; i < 10; ++i) u[i] = user_W[f[i] * DIM4 + d4];
#pragma unroll
        for (int i = 0; i < 10; ++i) {
            const float4 w = sh_rW[r[i] * DIM4 + d4];
            acc.x += u[i].x * w.x;
            acc.y += u[i].y * w.y;
            acc.z += u[i].z * w.z;
            acc.w += u[i].w * w.w;
        }
    }

    const int    iid = item_ids[b];
    const float4 iw  = item_W[iid * DIM4 + d4];
    const float4 bs  = bias[d4];

    float4 o;
    o.x = acc.x + iw.x + bs.x;
    o.y = acc.y + iw.y + bs.y;
    o.z = acc.z + iw.z + bs.z;
    o.w = acc.w + iw.w + bs.w;
    out[b * DIM4 + d4] = o;
}

extern "C" void kernel_launch(void* const* d_in, const int* in_sizes, int n_in,
                              void* d_out, int out_size, void* d_ws, size_t ws_size,
                              hipStream_t stream) {
    const int*    feature_ids = (const int*)   d_in[0];
    const float*  ratings     = (const float*) d_in[1];
    // d_in[2] = segment_ids: unused (segments contiguous by construction)
    const int*    item_ids    = (const int*)   d_in[3];
    const float4* user_W      = (const float4*)d_in[4];
    const float4* rating_W    = (const float4*)d_in[5];
    const float4* item_W      = (const float4*)d_in[6];
    const float4* bias        = (const float4*)d_in[7];
    float4*       out         = (float4*)      d_out;

    const size_t need = UT_BYTES + (size_t)TOTAL * sizeof(int); // ~28.9 MB
    if (d_ws != nullptr && ws_size >= need) {
        u32x4* uT     = (u32x4*)d_ws;
        int*   packed = (int*)((char*)d_ws + UT_BYTES);

        convert_pack_kernel<<<dim3(2048, 2), dim3(256), 0, stream>>>(
            user_W, feature_ids, ratings, uT, packed);

        features_linear_sliced<<<dim3((BATCH / RPB) * SLICES), dim3(BLOCK), 0, stream>>>(
            packed, item_ids, uT, (const float*)rating_W, item_W, bias, out);
    } else {
        features_linear_f32<<<dim3(BATCH / 8), dim3(BLOCK), 0, stream>>>(
            feature_ids, ratings, item_ids, user_W, rating_W, item_W, bias, out);
    }
}